// Round 3
// baseline (218.259 us; speedup 1.0000x reference)
//
#include <hip/hip_runtime.h>

// Problem constants (fixed by setup_inputs in the reference)
constexpr int N_  = 8;
constexpr int B_  = 64;
constexpr int C_  = 32;
constexpr int H_  = 256;
constexpr int W_  = 256;
constexpr int PH_ = 8;
constexpr int HW_ = H_ * W_;

// One thread = one sample point (nb, d, i, j); inner loop over 32 channels.
// grid = (N*B, ceil(2*PH*MW / 256)) -> ~2560 blocks for occupancy.
__global__ __launch_bounds__(256)
void boxpool_kernel(const float* __restrict__ x, const float* __restrict__ boxes,
                    float* __restrict__ out, int MW, long featsSize)
{
    const int nb  = blockIdx.x;         // 0..N*B-1
    const int n   = nb >> 6;            // B_ = 64
    const int tid = threadIdx.x;

    // Box parameters — wave-uniform address -> scalar loads
    const float* bp = boxes + (long)nb * 4;
    const float xmin = bp[0], ymin = bp[1], xmax = bp[2], ymax = bp[3];
    const bool is_zero = (xmin == 0.f) && (ymin == 0.f) && (xmax == 0.f) && (ymax == 0.f);
    const float bw = xmax - xmin, bh = ymax - ymin;
    const bool wide = bw > bh;
    float den = wide ? bh : bw;
    den = (den == 0.f) ? 1.f : den;
    const float ratio = (wide ? bw : bh) / den;
    const float wf = ceilf(ratio * (float)PH_);
    const float wm1 = (wf > 1.f) ? (wf - 1.f) : 1.f;

    const float halfW = (float)W_ * 0.5f;
    const float halfH = (float)H_ * 0.5f;

    // widths tail: (N,B,2) — write once (first point-chunk only)
    if (blockIdx.y == 0 && tid < 2)
        out[featsSize + (long)nb * 2 + tid] = is_zero ? 0.f : wf;

    const int PM   = PH_ * MW;          // per-channel slice
    const int npts = 2 * PM;            // both directions

    const int p = blockIdx.y * 256 + tid;
    if (p >= npts) return;

    int d = p / PM;
    int r = p - d * PM;
    int i = r / MW;
    int j = r - i * MW;

    // out index: (((nb*2+d)*C + c)*PH + i)*MW + j -> base at c=0, stride PM
    float* op = out + (long)(nb * 2 + d) * C_ * PM + (long)i * MW + j;

    const bool valid = !is_zero && ((float)j < wf);
    if (!valid) {
        #pragma unroll 8
        for (int c = 0; c < C_; ++c) op[(long)c * PM] = 0.f;
        return;
    }

    float fi = (float)i, fj = (float)j;
    if (d == 1) { fi = (float)(PH_ - 1) - fi; fj = wf - 1.f - fj; }

    float gx, gy;
    if (wide) {
        float each_w = bw / wm1;
        float each_h = bh / (float)(PH_ - 1);
        gx = (xmin + fj * each_w - halfW) / halfW;
        gy = (ymin + fi * each_h - halfH) / halfH;
    } else {
        float each_w = bh / wm1;
        float each_h = bw / (float)(PH_ - 1);
        gx = (xmin + fi * each_h - halfW) / halfW;
        gy = ((wf - fj) * each_w + ymin - halfH) / halfH;
    }

    // grid_sample: bilinear, zeros padding, align_corners=False
    float ix = ((gx + 1.f) * (float)W_ - 1.f) * 0.5f;
    float iy = ((gy + 1.f) * (float)H_ - 1.f) * 0.5f;
    float x0f = floorf(ix);
    float y0f = floorf(iy);

    float wx1 = ix - x0f, wx0 = 1.f - wx1;
    float wy1 = iy - y0f, wy0 = 1.f - wy1;

    bool vx0 = (x0f >= 0.f) && (x0f < (float)W_);
    bool vx1 = (x0f + 1.f >= 0.f) && (x0f + 1.f < (float)W_);
    bool vy0 = (y0f >= 0.f) && (y0f < (float)H_);
    bool vy1 = (y0f + 1.f >= 0.f) && (y0f + 1.f < (float)H_);
    if (!vx0) wx0 = 0.f;
    if (!vx1) wx1 = 0.f;
    if (!vy0) wy0 = 0.f;
    if (!vy1) wy1 = 0.f;

    int x0c = (int)fminf(fmaxf(x0f,       0.f), (float)(W_ - 1));
    int x1c = (int)fminf(fmaxf(x0f + 1.f, 0.f), (float)(W_ - 1));
    int y0c = (int)fminf(fmaxf(y0f,       0.f), (float)(H_ - 1));
    int y1c = (int)fminf(fmaxf(y0f + 1.f, 0.f), (float)(H_ - 1));

    int o00 = y0c * W_ + x0c;
    int o01 = y0c * W_ + x1c;
    int o10 = y1c * W_ + x0c;
    int o11 = y1c * W_ + x1c;

    float w00 = wx0 * wy0, w01 = wx1 * wy0;
    float w10 = wx0 * wy1, w11 = wx1 * wy1;

    const float* xc = x + (long)n * C_ * HW_;
    #pragma unroll 8
    for (int c = 0; c < C_; ++c) {
        float acc = w00 * xc[o00] + w01 * xc[o01]
                  + w10 * xc[o10] + w11 * xc[o11];
        op[(long)c * PM] = acc;
        xc += HW_;
    }
}

extern "C" void kernel_launch(void* const* d_in, const int* in_sizes, int n_in,
                              void* d_out, int out_size, void* d_ws, size_t ws_size,
                              hipStream_t stream)
{
    const float* x     = (const float*)d_in[0];
    const float* boxes = (const float*)d_in[1];
    float* out = (float*)d_out;

    long total      = (long)out_size;
    long widthsSize = (long)N_ * B_ * 2;
    long featsSize  = total - widthsSize;
    int  MW         = (int)(featsSize / ((long)N_ * B_ * 2 * C_ * PH_));

    int npts    = 2 * PH_ * MW;
    int pchunks = (npts + 255) / 256;

    hipLaunchKernelGGL(boxpool_kernel, dim3(N_ * B_, pchunks), dim3(256), 0, stream,
                       x, boxes, out, MW, featsSize);
}

// Round 4
// 90.437 us; speedup vs baseline: 2.4134x; 2.4134x over previous
//
#include <hip/hip_runtime.h>

// Problem constants (fixed by setup_inputs in the reference)
constexpr int N_  = 8;
constexpr int B_  = 64;
constexpr int C_  = 32;
constexpr int H_  = 256;
constexpr int W_  = 256;
constexpr int PH_ = 8;
constexpr int HW_ = H_ * W_;
constexpr int NB_ = N_ * B_;

// ---------------------------------------------------------------------------
// Kernel A: per sample point (nb, d, i, j) compute bilinear weights (float4)
// and clamped gather offsets (int4) into workspace. Invalid points get
// weights=0 / offsets=0 so the apply kernel is branch-free.
// Also writes the widths tail of the output.
// ---------------------------------------------------------------------------
__global__ __launch_bounds__(256)
void setup_kernel(const float* __restrict__ boxes, float* __restrict__ out,
                  float4* __restrict__ wts, int4* __restrict__ offs,
                  int MW, int PM, unsigned M16, long featsSize)
{
    const int nb  = blockIdx.x;         // 0..NB-1
    const int tid = threadIdx.x;

    const float* bp = boxes + nb * 4;
    const float xmin = bp[0], ymin = bp[1], xmax = bp[2], ymax = bp[3];
    const bool is_zero = (xmin == 0.f) && (ymin == 0.f) && (xmax == 0.f) && (ymax == 0.f);
    const float bw = xmax - xmin, bh = ymax - ymin;
    const bool wide = bw > bh;
    float den = wide ? bh : bw;
    den = (den == 0.f) ? 1.f : den;
    const float ratio = (wide ? bw : bh) / den;
    const float wf = ceilf(ratio * (float)PH_);
    const float wm1 = (wf > 1.f) ? (wf - 1.f) : 1.f;

    const float halfW = (float)W_ * 0.5f;
    const float halfH = (float)H_ * 0.5f;

    if (tid == 0) {
        float wv = is_zero ? 0.f : wf;
        out[featsSize + (long)nb * 2 + 0] = wv;
        out[featsSize + (long)nb * 2 + 1] = wv;
    }

    const int npts = 2 * PM;
    for (int p = tid; p < npts; p += 256) {
        int d = (p >= PM) ? 1 : 0;
        int r = p - d * PM;
        int i = (int)(((unsigned)r * M16) >> 16);   // r / MW via magic
        int j = r - i * MW;

        float4 w = make_float4(0.f, 0.f, 0.f, 0.f);
        int4   o = make_int4(0, 0, 0, 0);

        const bool valid = !is_zero && ((float)j < wf);
        if (valid) {
            float fi = (float)i, fj = (float)j;
            if (d == 1) { fi = (float)(PH_ - 1) - fi; fj = wf - 1.f - fj; }

            float gx, gy;
            if (wide) {
                float each_w = bw / wm1;
                float each_h = bh / (float)(PH_ - 1);
                gx = (xmin + fj * each_w - halfW) / halfW;
                gy = (ymin + fi * each_h - halfH) / halfH;
            } else {
                float each_w = bh / wm1;
                float each_h = bw / (float)(PH_ - 1);
                gx = (xmin + fi * each_h - halfW) / halfW;
                gy = ((wf - fj) * each_w + ymin - halfH) / halfH;
            }

            float ix = ((gx + 1.f) * (float)W_ - 1.f) * 0.5f;
            float iy = ((gy + 1.f) * (float)H_ - 1.f) * 0.5f;
            float x0f = floorf(ix);
            float y0f = floorf(iy);

            float wx1 = ix - x0f, wx0 = 1.f - wx1;
            float wy1 = iy - y0f, wy0 = 1.f - wy1;

            bool vx0 = (x0f >= 0.f) && (x0f < (float)W_);
            bool vx1 = (x0f + 1.f >= 0.f) && (x0f + 1.f < (float)W_);
            bool vy0 = (y0f >= 0.f) && (y0f < (float)H_);
            bool vy1 = (y0f + 1.f >= 0.f) && (y0f + 1.f < (float)H_);
            if (!vx0) wx0 = 0.f;
            if (!vx1) wx1 = 0.f;
            if (!vy0) wy0 = 0.f;
            if (!vy1) wy1 = 0.f;

            int x0c = (int)fminf(fmaxf(x0f,       0.f), (float)(W_ - 1));
            int x1c = (int)fminf(fmaxf(x0f + 1.f, 0.f), (float)(W_ - 1));
            int y0c = (int)fminf(fmaxf(y0f,       0.f), (float)(H_ - 1));
            int y1c = (int)fminf(fmaxf(y0f + 1.f, 0.f), (float)(H_ - 1));

            w = make_float4(wx0 * wy0, wx1 * wy0, wx0 * wy1, wx1 * wy1);
            o = make_int4(y0c * W_ + x0c, y0c * W_ + x1c,
                          y1c * W_ + x0c, y1c * W_ + x1c);
        }

        long pi = (long)nb * npts + p;
        wts[pi]  = w;
        offs[pi] = o;
    }
}

// ---------------------------------------------------------------------------
// Kernel B: one thread per feats element. Branch-free: load params, 4 gathers,
// 4 FMA, 1 store. t = (((nb*2+d)*C + c)*PM + pm), pm = i*MW+j.
// ---------------------------------------------------------------------------
__global__ __launch_bounds__(256)
void apply_kernel(const float* __restrict__ x, const float4* __restrict__ wts,
                  const int4* __restrict__ offs, float* __restrict__ out,
                  int PM, unsigned long long Mdiv, long featsSize)
{
    long t = (long)blockIdx.x * 256 + threadIdx.x;
    if (t >= featsSize) return;

    unsigned q1 = (unsigned)(((unsigned long long)t * Mdiv) >> 38);  // t / PM
    int      pm = (int)(t - (long)q1 * PM);
    unsigned c  = q1 & 31u;
    unsigned q2 = q1 >> 5;               // nb*2 + d

    long ppt = (long)q2 * PM + pm;       // param point index
    float4 w = wts[ppt];
    int4   o = offs[ppt];

    // image plane: n*C + c, n = nb>>6 = q2>>7
    const float* xp = x + (long)(((q2 >> 7) << 5) | c) * HW_;

    float acc = w.x * xp[o.x] + w.y * xp[o.y]
              + w.z * xp[o.z] + w.w * xp[o.w];
    out[t] = acc;
}

// ---------------------------------------------------------------------------
// Fallback (round-1 monolithic, known-correct) if workspace is too small.
// ---------------------------------------------------------------------------
__global__ __launch_bounds__(256)
void boxpool_mono(const float* __restrict__ x, const float* __restrict__ boxes,
                  float* __restrict__ out, int MW, long featsSize, long total)
{
    const float halfW = (float)W_ * 0.5f;
    const float halfH = (float)H_ * 0.5f;
    const long stride = (long)gridDim.x * 256;

    for (long idx = (long)blockIdx.x * 256 + threadIdx.x; idx < total; idx += stride) {
        if (idx >= featsSize) {
            long wq = idx - featsSize;
            int b = (int)((wq >> 1) % B_);
            int n = (int)((wq >> 1) / B_);
            const float* bp = boxes + ((long)(n * B_ + b)) * 4;
            float xmin = bp[0], ymin = bp[1], xmax = bp[2], ymax = bp[3];
            bool is_zero = (xmin == 0.f) && (ymin == 0.f) && (xmax == 0.f) && (ymax == 0.f);
            float bw = xmax - xmin, bh = ymax - ymin;
            bool wide = bw > bh;
            float den = wide ? bh : bw;
            den = (den == 0.f) ? 1.f : den;
            float ratio = (wide ? bw : bh) / den;
            out[idx] = is_zero ? 0.f : ceilf(ratio * (float)PH_);
            continue;
        }
        int j = (int)(idx % MW);
        long t = idx / MW;
        int i = (int)(t & 7);  t >>= 3;
        int c = (int)(t & 31); t >>= 5;
        int d = (int)(t & 1);  t >>= 1;
        int b = (int)(t % B_);
        int n = (int)(t / B_);

        const float* bp = boxes + ((long)(n * B_ + b)) * 4;
        float xmin = bp[0], ymin = bp[1], xmax = bp[2], ymax = bp[3];
        bool is_zero = (xmin == 0.f) && (ymin == 0.f) && (xmax == 0.f) && (ymax == 0.f);
        float bw = xmax - xmin, bh = ymax - ymin;
        bool wide = bw > bh;
        float den = wide ? bh : bw;
        den = (den == 0.f) ? 1.f : den;
        float ratio = (wide ? bw : bh) / den;
        float wf = ceilf(ratio * (float)PH_);

        bool valid = ((float)j < wf) && !is_zero;
        if (!valid) { out[idx] = 0.f; continue; }

        float wm1 = (wf > 1.f) ? (wf - 1.f) : 1.f;
        float fi = (float)i, fj = (float)j;
        if (d == 1) { fi = (float)(PH_ - 1) - fi; fj = wf - 1.f - fj; }

        float gx, gy;
        if (wide) {
            float each_w = bw / wm1;
            float each_h = bh / (float)(PH_ - 1);
            gx = (xmin + fj * each_w - halfW) / halfW;
            gy = (ymin + fi * each_h - halfH) / halfH;
        } else {
            float each_w = bh / wm1;
            float each_h = bw / (float)(PH_ - 1);
            gx = (xmin + fi * each_h - halfW) / halfW;
            gy = ((wf - fj) * each_w + ymin - halfH) / halfH;
        }

        float ix = ((gx + 1.f) * (float)W_ - 1.f) * 0.5f;
        float iy = ((gy + 1.f) * (float)H_ - 1.f) * 0.5f;
        float x0f = floorf(ix);
        float y0f = floorf(iy);

        const float* xp = x + ((long)(n * C_ + c)) * (long)HW_;
        float acc = 0.f;
        #pragma unroll
        for (int dy = 0; dy <= 1; ++dy) {
            float yif = y0f + (float)dy;
            float wy  = 1.f - fabsf(iy - yif);
            bool  vy  = (yif >= 0.f) && (yif < (float)H_);
            int   yc  = (int)fminf(fmaxf(yif, 0.f), (float)(H_ - 1));
            #pragma unroll
            for (int dx = 0; dx <= 1; ++dx) {
                float xif = x0f + (float)dx;
                float wx  = 1.f - fabsf(ix - xif);
                bool  vx  = (xif >= 0.f) && (xif < (float)W_);
                int   xc  = (int)fminf(fmaxf(xif, 0.f), (float)(W_ - 1));
                if (vx && vy) acc += xp[(long)yc * W_ + xc] * (wx * wy);
            }
        }
        out[idx] = acc;
    }
}

extern "C" void kernel_launch(void* const* d_in, const int* in_sizes, int n_in,
                              void* d_out, int out_size, void* d_ws, size_t ws_size,
                              hipStream_t stream)
{
    const float* x     = (const float*)d_in[0];
    const float* boxes = (const float*)d_in[1];
    float* out = (float*)d_out;

    long total      = (long)out_size;
    long widthsSize = (long)N_ * B_ * 2;
    long featsSize  = total - widthsSize;
    int  MW         = (int)(featsSize / ((long)N_ * B_ * 2 * C_ * PH_));
    int  PM         = PH_ * MW;
    long nptsTotal  = (long)NB_ * 2 * PM;

    size_t need = (size_t)nptsTotal * (sizeof(float4) + sizeof(int4));
    if (ws_size < need) {
        // fallback: monolithic kernel (round-1 performance)
        hipLaunchKernelGGL(boxpool_mono, dim3(2048), dim3(256), 0, stream,
                           x, boxes, out, MW, featsSize, total);
        return;
    }

    float4* wts  = (float4*)d_ws;
    int4*   offs = (int4*)((char*)d_ws + (size_t)nptsTotal * sizeof(float4));

    unsigned M16 = (65536u + (unsigned)MW - 1u) / (unsigned)MW;           // r/MW
    unsigned long long Mdiv =
        ((1ull << 38) + (unsigned long long)PM - 1ull) / (unsigned long long)PM;  // t/PM

    hipLaunchKernelGGL(setup_kernel, dim3(NB_), dim3(256), 0, stream,
                       boxes, out, wts, offs, MW, PM, M16, featsSize);

    long blocksB = (featsSize + 255) / 256;
    hipLaunchKernelGGL(apply_kernel, dim3((unsigned)blocksB), dim3(256), 0, stream,
                       x, wts, offs, out, PM, Mdiv, featsSize);
}

// Round 5
// 61.156 us; speedup vs baseline: 3.5689x; 1.4788x over previous
//
#include <hip/hip_runtime.h>

// Problem constants (fixed by setup_inputs in the reference)
constexpr int N_  = 8;
constexpr int B_  = 64;
constexpr int C_  = 32;
constexpr int H_  = 256;
constexpr int W_  = 256;
constexpr int PH_ = 8;
constexpr int HW_ = H_ * W_;
constexpr int NB_ = N_ * B_;
constexpr int CPT_ = 8;           // channels per thread
constexpr int CB_  = C_ / CPT_;   // 4 channel-blocks (power of 2)

// 8-byte load at 4-byte alignment (unaligned-access-mode handles it; worst
// case the compiler splits it into two dword loads == old behavior).
struct __attribute__((packed, aligned(4))) f2u { float a, b; };

// One thread = one sample point (nb, i, j) x one channel-block (8 channels).
// Computes the bilinear sample once, stores to BOTH directions:
//   d=0 at (i, j)  and  d=1 at (7-i, wf-1-j)   (bijection on valid region).
__global__ __launch_bounds__(256)
void boxpool_v5(const float* __restrict__ x, const float* __restrict__ boxes,
                float* __restrict__ out, int MW, int PM,
                unsigned long long Mpm, unsigned M16, long featsSize, long U)
{
    const long u = (long)blockIdx.x * 256 + threadIdx.x;
    if (u >= U) return;

    // ---- decompose u = ((nb*CB + cb)*PM + pm), pm = i*MW + j
    unsigned q  = (unsigned)(((unsigned long long)u * Mpm) >> 38);  // u / PM
    int      pm = (int)(u - (long)q * PM);
    int      cb = (int)(q & (CB_ - 1));
    int      nb = (int)(q >> 2);                 // log2(CB_) = 2
    int      i  = (int)(((unsigned)pm * M16) >> 16);   // pm / MW
    int      j  = pm - i * MW;
    int      n  = nb >> 6;                       // B_ = 64

    // ---- box parameters
    const float* bp = boxes + (long)nb * 4;
    const float xmin = bp[0], ymin = bp[1], xmax = bp[2], ymax = bp[3];
    const bool is_zero = (xmin == 0.f) && (ymin == 0.f) && (xmax == 0.f) && (ymax == 0.f);
    const float bw = xmax - xmin, bh = ymax - ymin;
    const bool wide = bw > bh;
    float den = wide ? bh : bw;
    den = (den == 0.f) ? 1.f : den;
    const float ratio = (wide ? bw : bh) / den;
    const float wf = ceilf(ratio * (float)PH_);
    const float wm1 = (wf > 1.f) ? (wf - 1.f) : 1.f;

    // widths tail piggy-back: first NB_ threads write (N,B,2)
    if (u < NB_) {
        const float* bq = boxes + u * 4;
        bool z = (bq[0] == 0.f) && (bq[1] == 0.f) && (bq[2] == 0.f) && (bq[3] == 0.f);
        float bw2 = bq[2] - bq[0], bh2 = bq[3] - bq[1];
        bool wd = bw2 > bh2;
        float dn = wd ? bh2 : bw2;
        dn = (dn == 0.f) ? 1.f : dn;
        float wv = z ? 0.f : ceilf(((wd ? bw2 : bh2) / dn) * (float)PH_);
        out[featsSize + u * 2 + 0] = wv;
        out[featsSize + u * 2 + 1] = wv;
    }

    const int  c0 = cb * CPT_;
    const long obase = (long)nb * (2 * C_ * PM);
    float* o0p = out + obase + (long)c0 * PM + pm;                    // d=0 @ (i,j)

    const bool valid = !is_zero && ((float)j < wf);
    if (!valid) {
        float* o1p = out + obase + (long)(C_ + c0) * PM + pm;         // d=1 @ (i,j)
        #pragma unroll
        for (int k = 0; k < CPT_; ++k) {
            o0p[(long)k * PM] = 0.f;
            o1p[(long)k * PM] = 0.f;
        }
        return;
    }

    const int i2 = (PH_ - 1) - i;
    const int j2 = (int)wf - 1 - j;
    float* o1p = out + obase + (long)(C_ + c0) * PM + (long)i2 * MW + j2;  // d=1 @ flipped

    // ---- sample coordinates (pixels), forward grid at (i,j)
    const float fi = (float)i, fj = (float)j;
    float xs, ys;
    if (wide) {
        xs = xmin + fj * (bw / wm1);
        ys = ymin + fi * (bh * (1.f / (float)(PH_ - 1)));
    } else {
        xs = xmin + fi * (bw * (1.f / (float)(PH_ - 1)));
        ys = ymin + (wf - fj) * (bh / wm1);
    }
    // ix = ((gx+1)*W - 1)/2 with gx=(xs-halfW)/halfW  ==  xs - 0.5 exactly
    const float ix = xs - 0.5f;
    const float iy = ys - 0.5f;
    const float x0f = floorf(ix), y0f = floorf(iy);
    const int   x0  = (int)x0f,  y0  = (int)y0f;

    float wx1 = ix - x0f, wx0 = 1.f - wx1;
    float wy1 = iy - y0f, wy0 = 1.f - wy1;

    // y rows: clamp + zero-weight if out of bounds
    if (y0 < 0 || y0 >= H_)         wy0 = 0.f;
    if (y0 + 1 < 0 || y0 + 1 >= H_) wy1 = 0.f;
    const int y0c = min(max(y0, 0), H_ - 1);
    const int y1c = min(max(y0 + 1, 0), H_ - 1);

    // x pair: always adjacent; defensive base-clamp with weight reselect
    if (x0 < 0 || x0 >= W_)     wx0 = 0.f;
    if (x0 + 1 < 0 || x0 + 1 >= W_) wx1 = 0.f;
    const int bx = min(max(x0, 0), W_ - 2);
    const float wl = (bx == x0) ? wx0 : ((bx == x0 + 1) ? wx1 : 0.f);
    const float wr = (bx + 1 == x0 + 1) ? wx1 : ((bx + 1 == x0) ? wx0 : 0.f);

    const int o0 = y0c * W_ + bx;
    const int o1 = y1c * W_ + bx;
    const float w00 = wl * wy0, w01 = wr * wy0;
    const float w10 = wl * wy1, w11 = wr * wy1;

    // ---- 8 channels: 2x 8B gathers + 2 stores each
    const float* xp = x + (long)(n * C_ + c0) * HW_;
    #pragma unroll
    for (int k = 0; k < CPT_; ++k) {
        f2u r0 = *reinterpret_cast<const f2u*>(xp + o0);
        f2u r1 = *reinterpret_cast<const f2u*>(xp + o1);
        float v = w00 * r0.a + w01 * r0.b + w10 * r1.a + w11 * r1.b;
        o0p[(long)k * PM] = v;
        o1p[(long)k * PM] = v;
        xp += HW_;
    }
}

extern "C" void kernel_launch(void* const* d_in, const int* in_sizes, int n_in,
                              void* d_out, int out_size, void* d_ws, size_t ws_size,
                              hipStream_t stream)
{
    const float* x     = (const float*)d_in[0];
    const float* boxes = (const float*)d_in[1];
    float* out = (float*)d_out;

    long total      = (long)out_size;
    long widthsSize = (long)N_ * B_ * 2;
    long featsSize  = total - widthsSize;
    int  MW         = (int)(featsSize / ((long)N_ * B_ * 2 * C_ * PH_));
    int  PM         = PH_ * MW;

    long U = (long)NB_ * CB_ * PM;   // one thread per (nb, cb, point)

    unsigned long long Mpm =
        ((1ull << 38) + (unsigned long long)PM - 1ull) / (unsigned long long)PM;  // u/PM
    unsigned M16 = (65536u + (unsigned)MW - 1u) / (unsigned)MW;                   // pm/MW

    long blocks = (U + 255) / 256;
    hipLaunchKernelGGL(boxpool_v5, dim3((unsigned)blocks), dim3(256), 0, stream,
                       x, boxes, out, MW, PM, Mpm, M16, featsSize, U);
}

// Round 6
// 43.900 us; speedup vs baseline: 4.9718x; 1.3931x over previous
//
#include <hip/hip_runtime.h>

// Problem constants (fixed by setup_inputs in the reference)
constexpr int N_  = 8;
constexpr int B_  = 64;
constexpr int C_  = 32;
constexpr int H_  = 256;
constexpr int W_  = 256;
constexpr int PH_ = 8;
constexpr int HW_ = H_ * W_;
constexpr int NB_ = N_ * B_;
constexpr int CPT_ = 8;           // channels per thread
constexpr int CB_  = C_ / CPT_;   // 4 channel-blocks

// 8-byte load at 4-byte alignment.
struct __attribute__((packed, aligned(4))) f2u { float a, b; };

// One block = (nb, cb, pm-chunk). Block->box mapping is XCD-clustered:
//   xcd = blockIdx & 7, box = xcd*64 + seq/G  -> all G blocks of one box land
//   consecutively on one XCD (assuming round-robin dispatch; perf-only).
// One thread = one sample point x 8 channels. Sample computed once, stored to
// BOTH directions: d=0 at (i,j), d=1 at (7-i, wf-1-j).
__global__ __launch_bounds__(256)
void boxpool_v6(const float* __restrict__ x, const float* __restrict__ boxes,
                float* __restrict__ out, int MW, int PM, unsigned M16,
                int G, int pmb, long featsSize)
{
    const int Bx  = blockIdx.x;
    const int xcd = Bx & 7;
    const int s   = Bx >> 3;
    const int bq  = s / G;                 // box index within this XCD's share
    const int g   = s - bq * G;
    const int nb  = xcd * (NB_ / 8) + bq;  // 64 boxes per XCD
    const int cb  = g / pmb;
    const int pmblk = g - cb * pmb;
    const int tid = threadIdx.x;
    const int pm  = pmblk * 256 + tid;

    // ---- box parameters (nb uniform per block -> scalar loads)
    const float* bp = boxes + (long)nb * 4;
    const float xmin = bp[0], ymin = bp[1], xmax = bp[2], ymax = bp[3];
    const bool is_zero = (xmin == 0.f) && (ymin == 0.f) && (xmax == 0.f) && (ymax == 0.f);
    const float bw = xmax - xmin, bh = ymax - ymin;
    const bool wide = bw > bh;
    float den = wide ? bh : bw;
    den = (den == 0.f) ? 1.f : den;
    const float ratio = (wide ? bw : bh) / den;
    const float wf = ceilf(ratio * (float)PH_);
    const float wm1 = (wf > 1.f) ? (wf - 1.f) : 1.f;

    // widths tail (N,B,2): one writer per box
    if (g == 0 && tid == 0) {
        float wv = is_zero ? 0.f : wf;
        out[featsSize + (long)nb * 2 + 0] = wv;
        out[featsSize + (long)nb * 2 + 1] = wv;
    }

    if (pm >= PM) return;

    const int i = (int)(((unsigned)pm * M16) >> 16);   // pm / MW via magic
    const int j = pm - i * MW;
    const int n = nb >> 6;                             // B_ = 64
    const int c0 = cb * CPT_;

    const long obase = (long)nb * (2 * C_ * PM);
    float* o0p = out + obase + (long)c0 * PM + pm;                    // d=0 @ (i,j)

    const bool valid = !is_zero && ((float)j < wf);
    if (!valid) {
        float* o1p = out + obase + (long)(C_ + c0) * PM + pm;         // d=1 @ (i,j)
        #pragma unroll
        for (int k = 0; k < CPT_; ++k) {
            o0p[(long)k * PM] = 0.f;
            o1p[(long)k * PM] = 0.f;
        }
        return;
    }

    const int i2 = (PH_ - 1) - i;
    const int j2 = (int)wf - 1 - j;
    float* o1p = out + obase + (long)(C_ + c0) * PM + (long)i2 * MW + j2;  // d=1 @ flipped

    // ---- sample coordinates (pixels), forward grid at (i,j)
    const float fi = (float)i, fj = (float)j;
    float xs, ys;
    if (wide) {
        xs = xmin + fj * (bw / wm1);
        ys = ymin + fi * (bh * (1.f / (float)(PH_ - 1)));
    } else {
        xs = xmin + fi * (bw * (1.f / (float)(PH_ - 1)));
        ys = ymin + (wf - fj) * (bh / wm1);
    }
    const float ix = xs - 0.5f;   // ((gx+1)*W - 1)/2 == xs - 0.5 exactly
    const float iy = ys - 0.5f;
    const float x0f = floorf(ix), y0f = floorf(iy);
    const int   x0  = (int)x0f,  y0  = (int)y0f;

    float wx1 = ix - x0f, wx0 = 1.f - wx1;
    float wy1 = iy - y0f, wy0 = 1.f - wy1;

    if (y0 < 0 || y0 >= H_)         wy0 = 0.f;
    if (y0 + 1 < 0 || y0 + 1 >= H_) wy1 = 0.f;
    const int y0c = min(max(y0, 0), H_ - 1);
    const int y1c = min(max(y0 + 1, 0), H_ - 1);

    if (x0 < 0 || x0 >= W_)         wx0 = 0.f;
    if (x0 + 1 < 0 || x0 + 1 >= W_) wx1 = 0.f;
    const int bx = min(max(x0, 0), W_ - 2);
    const float wl = (bx == x0) ? wx0 : ((bx == x0 + 1) ? wx1 : 0.f);
    const float wr = (bx + 1 == x0 + 1) ? wx1 : ((bx + 1 == x0) ? wx0 : 0.f);

    const int o0 = y0c * W_ + bx;
    const int o1 = y1c * W_ + bx;
    const float w00 = wl * wy0, w01 = wr * wy0;
    const float w10 = wl * wy1, w11 = wr * wy1;

    // ---- phase 1: issue all 16 gathers (independent, stay in flight)
    const float* xp = x + (long)(n * C_ + c0) * HW_;
    f2u r0[CPT_], r1[CPT_];
    #pragma unroll
    for (int k = 0; k < CPT_; ++k) {
        r0[k] = *reinterpret_cast<const f2u*>(xp + o0);
        r1[k] = *reinterpret_cast<const f2u*>(xp + o1);
        xp += HW_;
    }

    // ---- phase 2: compute + store both directions
    #pragma unroll
    for (int k = 0; k < CPT_; ++k) {
        float v = w00 * r0[k].a + w01 * r0[k].b + w10 * r1[k].a + w11 * r1[k].b;
        o0p[(long)k * PM] = v;
        o1p[(long)k * PM] = v;
    }
}

extern "C" void kernel_launch(void* const* d_in, const int* in_sizes, int n_in,
                              void* d_out, int out_size, void* d_ws, size_t ws_size,
                              hipStream_t stream)
{
    const float* x     = (const float*)d_in[0];
    const float* boxes = (const float*)d_in[1];
    float* out = (float*)d_out;

    long total      = (long)out_size;
    long widthsSize = (long)N_ * B_ * 2;
    long featsSize  = total - widthsSize;
    int  MW         = (int)(featsSize / ((long)N_ * B_ * 2 * C_ * PH_));
    int  PM         = PH_ * MW;

    int pmb = (PM + 255) / 256;       // pm-chunks per (nb, cb)
    int G   = CB_ * pmb;              // blocks per box
    int blocks = NB_ * G;             // divisible by 8 (NB_=512)

    unsigned M16 = (65536u + (unsigned)MW - 1u) / (unsigned)MW;   // pm/MW magic

    hipLaunchKernelGGL(boxpool_v6, dim3(blocks), dim3(256), 0, stream,
                       x, boxes, out, MW, PM, M16, G, pmb, featsSize);
}